// Round 8
// baseline (443.955 us; speedup 1.0000x reference)
//
#include <hip/hip_runtime.h>
#include <hip/hip_bf16.h>

// Problem: B=32, T=256, I=128, H=128, C=100. All fp32.
// out = (h_T + attn_c_final) @ w_fc.T + b_fc; only the LAST step's attention
// matters (scan carry overwrites attn_c each step).

#define Bsz 32
#define Tsz 256
#define Isz 128
#define Hsz 128
#define Csz 100
#define G4H 512   // 4*H

typedef short v8s __attribute__((ext_vector_type(8)));   // 8 bf16 = 4 VGPRs
typedef float v4fa __attribute__((ext_vector_type(4)));  // MFMA acc

// ---------------- device helpers ----------------
__device__ __forceinline__ float quad_rsum(float x) {
    int t = __builtin_amdgcn_update_dpp(0, __float_as_int(x), 0xB1, 0xF, 0xF, true); // xor 1
    x += __int_as_float(t);
    t = __builtin_amdgcn_update_dpp(0, __float_as_int(x), 0x4E, 0xF, 0xF, true);     // xor 2
    x += __int_as_float(t);
    return x;
}
__device__ __forceinline__ float rcpf(float x) { return __builtin_amdgcn_rcpf(x); }
__device__ __forceinline__ float ex2(float x) { return __builtin_amdgcn_exp2f(x); }
// sigmoid = 1/(1+2^(-x*log2e))  : 4-op chain (mul, exp, add, rcp)
__device__ __forceinline__ float sigm_n(float x) {
    return rcpf(1.0f + ex2(-1.442695041f * x));
}
// tanh(x) = 1 - 2/(1+e^{2x}) : 5-op chain. Accurate ~1e-7, correct at +-inf.
__device__ __forceinline__ float tanh_n(float x) {
    return fmaf(-2.0f, rcpf(1.0f + ex2(2.885390082f * x)), 1.0f);
}
__device__ __forceinline__ short bf16_bits(float x) {
    __hip_bfloat16 h = __float2bfloat16(x);
    return *reinterpret_cast<short*>(&h);
}
__device__ __forceinline__ float bf16_val(float x) {
    return __bfloat162float(__float2bfloat16(x));
}

// ---------------- kernel 0: weight prep ----------------
// W2ih / W2hh [n][k'] (512 x 384 bf16): [w_hi | w_lo | w_hi] split layout.
// W2v [n][k'] (128 x 384 bf16): transpose-split of w1 bottom half.
// bias = b_ih + b_hh (folded into G). attn_c zeroed.
__global__ __launch_bounds__(256) void prep_kernel(
    const float* __restrict__ w_ih, const float* __restrict__ b_ih,
    const float* __restrict__ w_hh, const float* __restrict__ b_hh,
    const float* __restrict__ w1,
    __hip_bfloat16* __restrict__ W2ih, __hip_bfloat16* __restrict__ W2hh,
    __hip_bfloat16* __restrict__ W2v,
    float* __restrict__ bias, float* __restrict__ attn_c) {
    int idx = blockIdx.x * blockDim.x + threadIdx.x;   // 0..65535
    if (idx < G4H * Isz) {
        int n = idx >> 7;
        int k = idx & 127;
        {
            float x = w_ih[idx];
            __hip_bfloat16 hi = __float2bfloat16(x);
            __hip_bfloat16 lo = __float2bfloat16(x - __bfloat162float(hi));
            W2ih[(size_t)n * 384 + k] = hi;
            W2ih[(size_t)n * 384 + 128 + k] = lo;
            W2ih[(size_t)n * 384 + 256 + k] = hi;
        }
        {
            float x = w_hh[idx];    // w_hh is [512][128] row-major, same shape
            __hip_bfloat16 hi = __float2bfloat16(x);
            __hip_bfloat16 lo = __float2bfloat16(x - __bfloat162float(hi));
            W2hh[(size_t)n * 384 + k] = hi;
            W2hh[(size_t)n * 384 + 128 + k] = lo;
            W2hh[(size_t)n * 384 + 256 + k] = hi;
        }
    }
    if (idx < Hsz * Hsz) {
        int n = idx >> 7;          // output col of KV
        int k = idx & 127;
        float x = w1[(size_t)(128 + k) * Hsz + n];
        __hip_bfloat16 hi = __float2bfloat16(x);
        __hip_bfloat16 lo = __float2bfloat16(x - __bfloat162float(hi));
        W2v[(size_t)n * 384 + k] = hi;
        W2v[(size_t)n * 384 + 128 + k] = lo;
        W2v[(size_t)n * 384 + 256 + k] = hi;
    }
    if (idx < G4H) bias[idx] = b_ih[idx] + b_hh[idx];
    if (idx < Bsz * Hsz) attn_c[idx] = 0.0f;
}

// ---------------- gemm_mfma_f32a: C[M,N] = split(A_fp32) @ split(W)^T (+bias) ----
__global__ __launch_bounds__(256) void gemm_mfma_f32a(
    const float* __restrict__ A, const __hip_bfloat16* __restrict__ W2,
    const float* __restrict__ bias, float* __restrict__ C, int M, int N) {
    const int tid = threadIdx.x;
    const int w = tid >> 6, lane = tid & 63;
    const int m0 = blockIdx.y * 64 + (w & 1) * 32;
    const int n0 = blockIdx.x * 64 + (w >> 1) * 32;
    const int r = lane & 15, quad = lane >> 4;

    v8s Ahi[2][4], Alo[2][4];
    #pragma unroll
    for (int i = 0; i < 2; ++i)
        #pragma unroll
        for (int cb = 0; cb < 4; ++cb) {
            const float* src = A + (size_t)(m0 + 16 * i + r) * Isz + cb * 32 + quad * 8;
            float4 f0 = *(const float4*)src;
            float4 f1 = *(const float4*)(src + 4);
            float f[8] = {f0.x, f0.y, f0.z, f0.w, f1.x, f1.y, f1.z, f1.w};
            v8s hi, lo;
            #pragma unroll
            for (int e = 0; e < 8; ++e) {
                float hv = bf16_val(f[e]);
                hi[e] = bf16_bits(f[e]);
                lo[e] = bf16_bits(f[e] - hv);
            }
            Ahi[i][cb] = hi;
            Alo[i][cb] = lo;
        }

    v4fa acc[2][2] = {};
    const short* Wb = (const short*)W2;
    #pragma unroll
    for (int ks = 0; ks < 12; ++ks) {
        int cb = ks & 3;
        v8s a0 = (ks >= 8) ? Alo[0][cb] : Ahi[0][cb];
        v8s a1 = (ks >= 8) ? Alo[1][cb] : Ahi[1][cb];
        int kb = ks * 32 + quad * 8;
        v8s b0 = *(const v8s*)(Wb + (size_t)(n0 + r) * 384 + kb);
        v8s b1 = *(const v8s*)(Wb + (size_t)(n0 + 16 + r) * 384 + kb);
        acc[0][0] = __builtin_amdgcn_mfma_f32_16x16x32_bf16(a0, b0, acc[0][0], 0, 0, 0);
        acc[0][1] = __builtin_amdgcn_mfma_f32_16x16x32_bf16(a0, b1, acc[0][1], 0, 0, 0);
        acc[1][0] = __builtin_amdgcn_mfma_f32_16x16x32_bf16(a1, b0, acc[1][0], 0, 0, 0);
        acc[1][1] = __builtin_amdgcn_mfma_f32_16x16x32_bf16(a1, b1, acc[1][1], 0, 0, 0);
    }
    // C/D layout: col = lane&15, row = quad*4 + reg  [verified m89/m91]
    #pragma unroll
    for (int i = 0; i < 2; ++i)
        #pragma unroll
        for (int j = 0; j < 2; ++j) {
            int cn = n0 + 16 * j + r;
            float bb = bias ? bias[cn] : 0.0f;
            #pragma unroll
            for (int rr = 0; rr < 4; ++rr) {
                int row = m0 + 16 * i + quad * 4 + rr;
                C[(size_t)row * N + cn] = acc[i][j][rr] + bb;
            }
        }
}

// ---------------- kernel 2: MFMA sequential LSTM ----------------
// One block = one batch, 512 thr = 8 waves. Wave w owns d in [w*16,w*16+16)
// for ALL 4 gates (N-tiles at g*128+w*16): i,f,g,o for a given d land on
// the SAME lane (C/D: col=lane&15; row0 = quad==0, reg0) -> no cross-lane
// gate combine at all. K=128 via the proven 12-kstep hi/lo bf16 split.
// WHY MFMA: r1/r3/r4/r5/r6 proved the allocator always parks a large
// loop-invariant weight array in AGPRs and NO VALU op can source AGPRs
// (r4 assembler error) -> VALU recurrence pays ~128 v_accvgpr_read per
// thread per step. MFMA legally sources A/B from AGPRs (ISA §10), so AGPR
// residence becomes free. Matrix pipe was 0% utilized.
// Per step: 48 MFMA/wave (96/SIMD ~ 465 cyc) overlapped with ~60 VALU.
// h broadcast via 128-elem bf16 hi/lo LDS arrays (quad-broadcast reads,
// conflict-free). Raw lgkm-only barrier per step (r2, proven).
__global__ __launch_bounds__(512, 2) void lstm_seq(
    const float* __restrict__ G, const __hip_bfloat16* __restrict__ W2hh,
    float* __restrict__ H_all) {
    const int b = blockIdx.x;
    const int tid = threadIdx.x;
    const int w = tid >> 6;        // wave -> d-range base w*16
    const int lane = tid & 63;
    const int r = lane & 15;       // frag row/col
    const int quad = lane >> 4;    // k-octet

    __shared__ alignas(16) short hhi[2][128];
    __shared__ alignas(16) short hlo[2][128];

    // B-frags: wb[g][j], j<4: w_hi k-block j; j>=4: w_lo k-block j-4.
    // 32 v8s = 128 regs; loop-invariant -> AGPRs; MFMA reads them in place.
    v8s wb[4][8];
    {
        const short* Wb = (const short*)W2hh;
        #pragma unroll
        for (int g = 0; g < 4; ++g)
            #pragma unroll
            for (int j = 0; j < 8; ++j) {
                int n = g * 128 + w * 16 + r;
                wb[g][j] = *(const v8s*)(Wb + (size_t)n * 384 + j * 32 + quad * 8);
            }
    }

    if (tid < 128) {
        hhi[0][tid] = 0; hlo[0][tid] = 0;
        hhi[1][tid] = 0; hlo[1][tid] = 0;
    }
    float c = 0.0f;

    const float* Gq = G + (size_t)b * Tsz * G4H + w * 16 + r;
    float* Hst = H_all + (size_t)b * Tsz * Hsz + w * 16 + r;

    // prefetch t=0 gate inits (valid on quad==0 lanes)
    float gv0 = 0.f, gv1 = 0.f, gv2 = 0.f, gv3 = 0.f;
    if (quad == 0) {
        gv0 = Gq[0]; gv1 = Gq[128]; gv2 = Gq[256]; gv3 = Gq[384];
    }
    __syncthreads();

    int cur = 0;
    for (int t = 0; t < Tsz; ++t) {
        // A-frags from LDS: 8 bf16 at k = cb*32 + quad*8 (quad-broadcast).
        // Every row of A equals h (all lanes in a quad-group read the same
        // 16B) -> every row of D equals the GEMV result; row 0 is used.
        v8s ahi[4], alo[4];
        #pragma unroll
        for (int cb = 0; cb < 4; ++cb) {
            ahi[cb] = *(const v8s*)&hhi[cur][cb * 32 + quad * 8];
            alo[cb] = *(const v8s*)&hlo[cur][cb * 32 + quad * 8];
        }

        // prefetch next step's G (stays in flight across the raw barrier)
        const int tn = (t < Tsz - 1) ? t + 1 : t;
        float gn0 = 0.f, gn1 = 0.f, gn2 = 0.f, gn3 = 0.f;
        if (quad == 0) {
            const float* Gt = Gq + (size_t)tn * G4H;
            gn0 = Gt[0]; gn1 = Gt[128]; gn2 = Gt[256]; gn3 = Gt[384];
        }

        // acc init: row0 (quad==0, reg0) = G value; rest 0
        v4fa acc0 = {}, acc1 = {}, acc2 = {}, acc3 = {};
        if (quad == 0) { acc0[0] = gv0; acc1[0] = gv1; acc2[0] = gv2; acc3[0] = gv3; }

        // 12 k-steps x 4 gates: ks0-3 hi*hi, 4-7 hi*lo, 8-11 lo*hi
        #pragma unroll
        for (int ks = 0; ks < 12; ++ks) {
            const int cb = ks & 3;
            const int j = (ks < 8) ? ks : ks - 8;
            v8s a = (ks >= 8) ? alo[cb] : ahi[cb];
            acc0 = __builtin_amdgcn_mfma_f32_16x16x32_bf16(a, wb[0][j], acc0, 0, 0, 0);
            acc1 = __builtin_amdgcn_mfma_f32_16x16x32_bf16(a, wb[1][j], acc1, 0, 0, 0);
            acc2 = __builtin_amdgcn_mfma_f32_16x16x32_bf16(a, wb[2][j], acc2, 0, 0, 0);
            acc3 = __builtin_amdgcn_mfma_f32_16x16x32_bf16(a, wb[3][j], acc3, 0, 0, 0);
        }

        // gates (meaningful on quad==0 lanes; others compute garbage)
        float iv = sigm_n(acc0[0]);
        float fv = sigm_n(acc1[0]);
        float gg = tanh_n(acc2[0]);
        float ov = sigm_n(acc3[0]);
        c = fmaf(fv, c, iv * gg);
        float h = ov * tanh_n(c);

        if (quad == 0) {
            float hv = bf16_val(h);
            hhi[cur ^ 1][w * 16 + r] = bf16_bits(h);
            hlo[cur ^ 1][w * 16 + r] = bf16_bits(h - hv);
            Hst[(size_t)t * Hsz] = h;
        }
        gv0 = gn0; gv1 = gn1; gv2 = gn2; gv3 = gn3;

        // raw barrier: wait LDS only; global load/store stay in flight
        __builtin_amdgcn_sched_barrier(0);
        asm volatile("s_waitcnt lgkmcnt(0)" ::: "memory");
        __builtin_amdgcn_s_barrier();
        __builtin_amdgcn_sched_barrier(0);
        cur ^= 1;
    }
}

// ---------------- kernel 3a: fused KV-gemm + scores, grid (4 jt x 32 b) ----
// (r5 tail, measured good: ~117us total tail)
__global__ __launch_bounds__(256) void kv_scores(
    const float* __restrict__ H_all, const __hip_bfloat16* __restrict__ W2v,
    const float* __restrict__ w1, const float* __restrict__ w2,
    float* __restrict__ attn_c) {
    const int b = blockIdx.x >> 2, jt = blockIdx.x & 3;
    const int tid = threadIdx.x;
    __shared__ float kv_s[64][132];
    __shared__ float hT[Hsz];
    __shared__ float q_s[Hsz];
    __shared__ float w2s[Hsz];
    __shared__ float s_s[64];
    __shared__ float part[2][Hsz];

    const float* Hb = H_all + (size_t)b * Tsz * Hsz;

    if (tid < Hsz) {
        hT[tid] = Hb[255 * Hsz + tid];
        w2s[tid] = w2[tid];
    }

    // ---- KV tile: rows jt*64..+64 of H @ W2v^T -> kv_s (64 x 128)
    {
        const int w = tid >> 6, lane = tid & 63;
        const int m0 = (w & 1) * 32;
        const int n0 = (w >> 1) * 32;
        const int r = lane & 15, quad = lane >> 4;
        const float* Abase = Hb + (size_t)(jt * 64) * Hsz;

        v8s Ahi[2][4], Alo[2][4];
        #pragma unroll
        for (int i = 0; i < 2; ++i)
            #pragma unroll
            for (int cb = 0; cb < 4; ++cb) {
                const float* src = Abase + (size_t)(m0 + 16 * i + r) * Hsz + cb * 32 + quad * 8;
                float4 f0 = *(const float4*)src;
                float4 f1 = *(const float4*)(src + 4);
                float f[8] = {f0.x, f0.y, f0.z, f0.w, f1.x, f1.y, f1.z, f1.w};
                v8s hi, lo;
                #pragma unroll
                for (int e = 0; e < 8; ++e) {
                    float hv = bf16_val(f[e]);
                    hi[e] = bf16_bits(f[e]);
                    lo[e] = bf16_bits(f[e] - hv);
                }
                Ahi[i][cb] = hi;
                Alo[i][cb] = lo;
            }

        v4fa acc[2][2][2] = {};   // [nhalf][i][j]
        const short* Wb = (const short*)W2v;
        #pragma unroll
        for (int ks = 0; ks < 12; ++ks) {
            int cb = ks & 3;
            v8s a0 = (ks >= 8) ? Alo[0][cb] : Ahi[0][cb];
            v8s a1 = (ks >= 8) ? Alo[1][cb] : Ahi[1][cb];
            int kb = ks * 32 + quad * 8;
            #pragma unroll
            for (int nh = 0; nh < 2; ++nh) {
                int nn = nh * 64 + n0;
                v8s b0 = *(const v8s*)(Wb + (size_t)(nn + r) * 384 + kb);
                v8s b1 = *(const v8s*)(Wb + (size_t)(nn + 16 + r) * 384 + kb);
                acc[nh][0][0] = __builtin_amdgcn_mfma_f32_16x16x32_bf16(a0, b0, acc[nh][0][0], 0, 0, 0);
                acc[nh][0][1] = __builtin_amdgcn_mfma_f32_16x16x32_bf16(a0, b1, acc[nh][0][1], 0, 0, 0);
                acc[nh][1][0] = __builtin_amdgcn_mfma_f32_16x16x32_bf16(a1, b0, acc[nh][1][0], 0, 0, 0);
                acc[nh][1][1] = __builtin_amdgcn_mfma_f32_16x16x32_bf16(a1, b1, acc[nh][1][1], 0, 0, 0);
            }
        }
        #pragma unroll
        for (int nh = 0; nh < 2; ++nh)
            #pragma unroll
            for (int i = 0; i < 2; ++i)
                #pragma unroll
                for (int j = 0; j < 2; ++j)
                    #pragma unroll
                    for (int rr = 0; rr < 4; ++rr)
                        kv_s[m0 + 16 * i + quad * 4 + rr][nh * 64 + n0 + 16 * j + r] =
                            acc[nh][i][j][rr];
    }
    __syncthreads();

    if (tid < Hsz) {
        float acc = 0.f;
        #pragma unroll 8
        for (int k = 0; k < Hsz; ++k) acc = fmaf(hT[k], w1[k * Hsz + tid], acc);
        q_s[tid] = acc;
    }
    __syncthreads();

    // scores: one quad per slot j (64 per block)
    const int jl = tid >> 2, ql = tid & 3;
    const int j = jt * 64 + jl;
    float p = 0.f;
    if (j < 255) {
        #pragma unroll 8
        for (int kk = 0; kk < 32; ++kk) {
            int k = ql * 32 + ((kk + ql) & 31);   // phase-rotated, conflict-free
            p = fmaf(tanh_n(q_s[k] + kv_s[jl][k]), w2s[k], p);
        }
    }
    p = quad_rsum(p);
    if (ql == 0) s_s[jl] = (j < 255) ? p : 0.0f;
    __syncthreads();

    // partial attn_c over this block's 64 slots (two 32-slot halves)
    {
        const int dd = tid & 127, half = tid >> 7;
        float acc = 0.f;
        #pragma unroll 4
        for (int u = 0; u < 32; ++u) {
            int lj = half * 32 + u;
            int jj = jt * 64 + lj;
            if (jj < 255) acc = fmaf(s_s[lj], Hb[(size_t)jj * Hsz + dd], acc);
        }
        part[half][dd] = acc;
    }
    __syncthreads();
    if (tid < Hsz) atomicAdd(&attn_c[b * Hsz + tid], part[0][tid] + part[1][tid]);
}

// ---------------- kernel 3b: final FC ----------------
__global__ __launch_bounds__(256) void fc_out(
    const float* __restrict__ H_all, const float* __restrict__ attn_c,
    const float* __restrict__ w_fc, const float* __restrict__ b_fc,
    float* __restrict__ out) {
    const int b = blockIdx.x, tid = threadIdx.x;
    __shared__ float r_s[Hsz];
    if (tid < Hsz)
        r_s[tid] = H_all[(size_t)b * Tsz * Hsz + 255 * Hsz + tid] + attn_c[b * Hsz + tid];
    __syncthreads();
    const int o = tid >> 1, half = tid & 1;
    float acc = 0.f;
    if (o < Csz) {
        const float* wr = w_fc + (size_t)o * Hsz + half * 64;
        const float* rr = r_s + half * 64;
        #pragma unroll 8
        for (int k = 0; k < 64; ++k) acc = fmaf(rr[k], wr[k], acc);
    }
    acc += __shfl_xor(acc, 1);
    if (half == 0 && o < Csz) out[b * Csz + o] = acc + b_fc[o];
}

// ---------------- launch ----------------
extern "C" void kernel_launch(void* const* d_in, const int* in_sizes, int n_in,
                              void* d_out, int out_size, void* d_ws, size_t ws_size,
                              hipStream_t stream) {
    const float* x    = (const float*)d_in[0];
    const float* w_ih = (const float*)d_in[1];
    const float* b_ih = (const float*)d_in[2];
    const float* w_hh = (const float*)d_in[3];
    const float* b_hh = (const float*)d_in[4];
    const float* w1   = (const float*)d_in[5];
    const float* w2   = (const float*)d_in[6];
    const float* w_fc = (const float*)d_in[7];
    const float* b_fc = (const float*)d_in[8];

    float* ws = (float*)d_ws;
    float* bias   = ws;                                // 512 f
    float* attn_c = bias + 512;                        // 4096 f
    __hip_bfloat16* W2ih = (__hip_bfloat16*)(attn_c + 4096);           // 98304 f
    __hip_bfloat16* W2hh = (__hip_bfloat16*)(attn_c + 4096 + 98304);   // 98304 f
    __hip_bfloat16* W2v  = (__hip_bfloat16*)(attn_c + 4096 + 196608);  // 24576 f
    float* G      = attn_c + 4096 + 196608 + 24576;    // 8192*512 = 4194304 f
    float* H_all  = G + 4194304;                       // 1048576 f
    // total ~5.45M floats ~= 21.8 MB

    prep_kernel<<<256, 256, 0, stream>>>(w_ih, b_ih, w_hh, b_hh, w1,
                                         W2ih, W2hh, W2v, bias, attn_c);

    dim3 gG(G4H / 64, (Bsz * Tsz) / 64);              // (8, 128)
    gemm_mfma_f32a<<<gG, 256, 0, stream>>>(x, W2ih, bias, G, Bsz * Tsz, G4H);

    lstm_seq<<<Bsz, 512, 0, stream>>>(G, W2hh, H_all);

    kv_scores<<<Bsz * 4, 256, 0, stream>>>(H_all, W2v, w1, w2, attn_c);

    fc_out<<<Bsz, 256, 0, stream>>>(H_all, attn_c, w_fc, b_fc, (float*)d_out);
}

// Round 9
// 320.542 us; speedup vs baseline: 1.3850x; 1.3850x over previous
//
#include <hip/hip_runtime.h>
#include <hip/hip_bf16.h>

// Problem: B=32, T=256, I=128, H=128, C=100. All fp32.
// out = (h_T + attn_c_final) @ w_fc.T + b_fc; only the LAST step's attention
// matters (scan carry overwrites attn_c each step).
//
// Composite of measured-best phases:
//  - lstm_seq: r2 structure (asm v_pk_fma_f32 + raw lgkm-only barrier), 202.5us
//  - tail: r5 fused kv_scores (KV-gemm tile in LDS + scores + partial attn),
//    117us for prep+gemmG+kv_scores+fc_out
// Recurrence wall (established r0-r8): VALU issue 768 + AGPR-copy tax 512
// (no VALU op sources AGPRs, r4 assembler proof) + latency/barrier ~600 =
// ~1900 cyc/step. MFMA alternative measured worse (3080 cyc/step, r8):
// per-SIMD MFMA throughput 19.4 cyc makes GEMV/batch-packed variants all
// >= the VALU wall. 202us is the practical floor for this phase.

#define Bsz 32
#define Tsz 256
#define Isz 128
#define Hsz 128
#define Csz 100
#define G4H 512   // 4*H

typedef short v8s __attribute__((ext_vector_type(8)));   // 8 bf16 = 4 VGPRs
typedef float v4fa __attribute__((ext_vector_type(4)));  // MFMA acc

// ---------------- device helpers ----------------
__device__ __forceinline__ float2 pk_fma(float2 a, float2 b, float2 c) {
    float2 d;
    asm("v_pk_fma_f32 %0, %1, %2, %3" : "=v"(d) : "v"(a), "v"(b), "v"(c));
    return d;
}
__device__ __forceinline__ float quad_rsum(float x) {
    int t = __builtin_amdgcn_update_dpp(0, __float_as_int(x), 0xB1, 0xF, 0xF, true); // xor 1
    x += __int_as_float(t);
    t = __builtin_amdgcn_update_dpp(0, __float_as_int(x), 0x4E, 0xF, 0xF, true);     // xor 2
    x += __int_as_float(t);
    return x;
}
__device__ __forceinline__ float rcpf(float x) { return __builtin_amdgcn_rcpf(x); }
__device__ __forceinline__ float ex2(float x) { return __builtin_amdgcn_exp2f(x); }
// sigmoid = 1/(1+2^(-x*log2e))  : 4-op chain (mul, exp, add, rcp)
__device__ __forceinline__ float sigm_n(float x) {
    return rcpf(1.0f + ex2(-1.442695041f * x));
}
// tanh(x) = 1 - 2/(1+e^{2x}) : 5-op chain. Accurate ~1e-7, correct at +-inf.
__device__ __forceinline__ float tanh_n(float x) {
    return fmaf(-2.0f, rcpf(1.0f + ex2(2.885390082f * x)), 1.0f);
}
__device__ __forceinline__ short bf16_bits(float x) {
    __hip_bfloat16 h = __float2bfloat16(x);
    return *reinterpret_cast<short*>(&h);
}
__device__ __forceinline__ float bf16_val(float x) {
    return __bfloat162float(__float2bfloat16(x));
}

// ---------------- kernel 0: weight prep ----------------
// whh_pk: packed for lstm (r2 layout). bias = b_ih + b_hh. attn_c zeroed.
// W2ih[n][k'] (512 x 384 bf16): [w_hi | w_lo | w_hi]  (pairs with A=[hi|hi|lo])
// W2v [n][k'] (128 x 384 bf16): transpose-split of w1 bottom half.
__global__ __launch_bounds__(256) void prep_kernel(
    const float* __restrict__ w_ih, const float* __restrict__ b_ih,
    const float* __restrict__ w_hh, const float* __restrict__ b_hh,
    const float* __restrict__ w1,
    __hip_bfloat16* __restrict__ W2ih, __hip_bfloat16* __restrict__ W2v,
    float* __restrict__ whh_pk, float* __restrict__ bias,
    float* __restrict__ attn_c) {
    int idx = blockIdx.x * blockDim.x + threadIdx.x;   // 0..65535
    if (idx < G4H * Isz) {
        int n = idx >> 7;
        int k = idx & 127;
        float x = w_ih[idx];
        __hip_bfloat16 hi = __float2bfloat16(x);
        __hip_bfloat16 lo = __float2bfloat16(x - __bfloat162float(hi));
        W2ih[(size_t)n * 384 + k] = hi;
        W2ih[(size_t)n * 384 + 128 + k] = lo;
        W2ih[(size_t)n * 384 + 256 + k] = hi;

        int j4  = idx & 3;
        int q   = (idx >> 2) & 3;
        int d   = (idx >> 4) & 127;
        int gi  = (idx >> 11) & 3;
        int kk4 = (idx >> 13) & 7;
        whh_pk[idx] = w_hh[(size_t)((gi << 7) + d) * 128 + (q << 5) + (kk4 << 2) + j4];
    }
    if (idx < Hsz * Hsz) {
        int n = idx >> 7;          // output col of KV
        int k = idx & 127;
        float x = w1[(size_t)(128 + k) * Hsz + n];
        __hip_bfloat16 hi = __float2bfloat16(x);
        __hip_bfloat16 lo = __float2bfloat16(x - __bfloat162float(hi));
        W2v[(size_t)n * 384 + k] = hi;
        W2v[(size_t)n * 384 + 128 + k] = lo;
        W2v[(size_t)n * 384 + 256 + k] = hi;
    }
    if (idx < G4H) bias[idx] = b_ih[idx] + b_hh[idx];
    if (idx < Bsz * Hsz) attn_c[idx] = 0.0f;
}

// ---------------- gemm_mfma_f32a: C[M,N] = split(A_fp32) @ split(W)^T (+bias) ----
__global__ __launch_bounds__(256) void gemm_mfma_f32a(
    const float* __restrict__ A, const __hip_bfloat16* __restrict__ W2,
    const float* __restrict__ bias, float* __restrict__ C, int M, int N) {
    const int tid = threadIdx.x;
    const int w = tid >> 6, lane = tid & 63;
    const int m0 = blockIdx.y * 64 + (w & 1) * 32;
    const int n0 = blockIdx.x * 64 + (w >> 1) * 32;
    const int r = lane & 15, quad = lane >> 4;

    v8s Ahi[2][4], Alo[2][4];
    #pragma unroll
    for (int i = 0; i < 2; ++i)
        #pragma unroll
        for (int cb = 0; cb < 4; ++cb) {
            const float* src = A + (size_t)(m0 + 16 * i + r) * Isz + cb * 32 + quad * 8;
            float4 f0 = *(const float4*)src;
            float4 f1 = *(const float4*)(src + 4);
            float f[8] = {f0.x, f0.y, f0.z, f0.w, f1.x, f1.y, f1.z, f1.w};
            v8s hi, lo;
            #pragma unroll
            for (int e = 0; e < 8; ++e) {
                float hv = bf16_val(f[e]);
                hi[e] = bf16_bits(f[e]);
                lo[e] = bf16_bits(f[e] - hv);
            }
            Ahi[i][cb] = hi;
            Alo[i][cb] = lo;
        }

    v4fa acc[2][2] = {};
    const short* Wb = (const short*)W2;
    #pragma unroll
    for (int ks = 0; ks < 12; ++ks) {
        int cb = ks & 3;
        v8s a0 = (ks >= 8) ? Alo[0][cb] : Ahi[0][cb];
        v8s a1 = (ks >= 8) ? Alo[1][cb] : Ahi[1][cb];
        int kb = ks * 32 + quad * 8;
        v8s b0 = *(const v8s*)(Wb + (size_t)(n0 + r) * 384 + kb);
        v8s b1 = *(const v8s*)(Wb + (size_t)(n0 + 16 + r) * 384 + kb);
        acc[0][0] = __builtin_amdgcn_mfma_f32_16x16x32_bf16(a0, b0, acc[0][0], 0, 0, 0);
        acc[0][1] = __builtin_amdgcn_mfma_f32_16x16x32_bf16(a0, b1, acc[0][1], 0, 0, 0);
        acc[1][0] = __builtin_amdgcn_mfma_f32_16x16x32_bf16(a1, b0, acc[1][0], 0, 0, 0);
        acc[1][1] = __builtin_amdgcn_mfma_f32_16x16x32_bf16(a1, b1, acc[1][1], 0, 0, 0);
    }
    // C/D layout: col = lane&15, row = quad*4 + reg  [verified m89/m91]
    #pragma unroll
    for (int i = 0; i < 2; ++i)
        #pragma unroll
        for (int j = 0; j < 2; ++j) {
            int cn = n0 + 16 * j + r;
            float bb = bias ? bias[cn] : 0.0f;
            #pragma unroll
            for (int rr = 0; rr < 4; ++rr) {
                int row = m0 + 16 * i + quad * 4 + rr;
                C[(size_t)row * N + cn] = acc[i][j][rr] + bb;
            }
        }
}

// ---------------- kernel 2: sequential LSTM (r2 structure, 202.5us) ----------------
#define HPAD(k) ((k) + 8 * ((k) >> 5))

__global__ __launch_bounds__(512, 2) void lstm_seq(
    const float* __restrict__ G, const float* __restrict__ whh_pk,
    float* __restrict__ H_all) {
    const int b = blockIdx.x;
    const int tid = threadIdx.x;
    const int d = tid >> 2;
    const int q = tid & 3;

    __shared__ float h_s[2][160];

    float2 w2v[4][16];
    {
        const float4* wp = (const float4*)whh_pk;
        #pragma unroll
        for (int kk4 = 0; kk4 < 8; ++kk4)
            #pragma unroll
            for (int gi = 0; gi < 4; ++gi) {
                float4 v = wp[((kk4 * 4 + gi) * 128 + d) * 4 + q];
                w2v[gi][kk4 * 2]     = make_float2(v.x, v.y);
                w2v[gi][kk4 * 2 + 1] = make_float2(v.z, v.w);
            }
    }

    if (tid < 320) ((float*)h_s)[tid] = 0.0f;
    float c = 0.0f;
    __syncthreads();   // once, before the loop: full drain is fine here

    const float* Gq = G + (size_t)b * Tsz * G4H + q * 128 + d;
    float* Hst = H_all + (size_t)b * Tsz * Hsz + d;

    float gval = Gq[0];
    int cur = 0;
    for (int t = 0; t < Tsz; ++t) {
        const int tn = (t < Tsz - 1) ? t + 1 : t;
        float ngval = Gq[(size_t)tn * G4H];   // prefetch; stays in flight
                                              // across the raw barrier

        float2 accA[4], accB[4];
        #pragma unroll
        for (int gi = 0; gi < 4; ++gi) {
            accA[gi] = make_float2(q == gi ? gval : 0.f, 0.f);
            accB[gi] = make_float2(0.f, 0.f);
        }
        const float4* hb4 = (const float4*)&h_s[cur][q * 40];  // HPAD(q*32)=q*40
        #pragma unroll
        for (int kk4 = 0; kk4 < 8; ++kk4) {
            float4 h4 = hb4[kk4];
            float2 hA = make_float2(h4.x, h4.y);
            float2 hB = make_float2(h4.z, h4.w);
            accA[0] = pk_fma(hA, w2v[0][2 * kk4], accA[0]);
            accA[1] = pk_fma(hA, w2v[1][2 * kk4], accA[1]);
            accA[2] = pk_fma(hA, w2v[2][2 * kk4], accA[2]);
            accA[3] = pk_fma(hA, w2v[3][2 * kk4], accA[3]);
            accB[0] = pk_fma(hB, w2v[0][2 * kk4 + 1], accB[0]);
            accB[1] = pk_fma(hB, w2v[1][2 * kk4 + 1], accB[1]);
            accB[2] = pk_fma(hB, w2v[2][2 * kk4 + 1], accB[2]);
            accB[3] = pk_fma(hB, w2v[3][2 * kk4 + 1], accB[3]);
        }
        float a0 = quad_rsum(accA[0].x + accA[0].y + accB[0].x + accB[0].y);
        float a1 = quad_rsum(accA[1].x + accA[1].y + accB[1].x + accB[1].y);
        float a2 = quad_rsum(accA[2].x + accA[2].y + accB[2].x + accB[2].y);
        float a3 = quad_rsum(accA[3].x + accA[3].y + accB[3].x + accB[3].y);

        float iv = sigm_n(a0);
        float fv = sigm_n(a1);
        float gv = tanh_n(a2);
        float ov = sigm_n(a3);
        c = fmaf(fv, c, iv * gv);
        float h = ov * tanh_n(c);

        if (q == 0) {
            h_s[cur ^ 1][HPAD(d)] = h;
            Hst[(size_t)t * Hsz] = h;
        }
        gval = ngval;
        // ---- raw barrier: wait LDS only, leave global load/store in flight
        __builtin_amdgcn_sched_barrier(0);
        asm volatile("s_waitcnt lgkmcnt(0)" ::: "memory");
        __builtin_amdgcn_s_barrier();
        __builtin_amdgcn_sched_barrier(0);
        cur ^= 1;
    }
}

// ---------------- kernel 3a: fused KV-gemm + scores, grid (4 jt x 32 b) ----
// (r5 tail, measured: tail total ~117us)
__global__ __launch_bounds__(256) void kv_scores(
    const float* __restrict__ H_all, const __hip_bfloat16* __restrict__ W2v,
    const float* __restrict__ w1, const float* __restrict__ w2,
    float* __restrict__ attn_c) {
    const int b = blockIdx.x >> 2, jt = blockIdx.x & 3;
    const int tid = threadIdx.x;
    __shared__ float kv_s[64][132];
    __shared__ float hT[Hsz];
    __shared__ float q_s[Hsz];
    __shared__ float w2s[Hsz];
    __shared__ float s_s[64];
    __shared__ float part[2][Hsz];

    const float* Hb = H_all + (size_t)b * Tsz * Hsz;

    if (tid < Hsz) {
        hT[tid] = Hb[255 * Hsz + tid];
        w2s[tid] = w2[tid];
    }

    // ---- KV tile: rows jt*64..+64 of H @ W2v^T -> kv_s (64 x 128)
    {
        const int w = tid >> 6, lane = tid & 63;
        const int m0 = (w & 1) * 32;
        const int n0 = (w >> 1) * 32;
        const int r = lane & 15, quad = lane >> 4;
        const float* Abase = Hb + (size_t)(jt * 64) * Hsz;

        v8s Ahi[2][4], Alo[2][4];
        #pragma unroll
        for (int i = 0; i < 2; ++i)
            #pragma unroll
            for (int cb = 0; cb < 4; ++cb) {
                const float* src = Abase + (size_t)(m0 + 16 * i + r) * Hsz + cb * 32 + quad * 8;
                float4 f0 = *(const float4*)src;
                float4 f1 = *(const float4*)(src + 4);
                float f[8] = {f0.x, f0.y, f0.z, f0.w, f1.x, f1.y, f1.z, f1.w};
                v8s hi, lo;
                #pragma unroll
                for (int e = 0; e < 8; ++e) {
                    float hv = bf16_val(f[e]);
                    hi[e] = bf16_bits(f[e]);
                    lo[e] = bf16_bits(f[e] - hv);
                }
                Ahi[i][cb] = hi;
                Alo[i][cb] = lo;
            }

        v4fa acc[2][2][2] = {};   // [nhalf][i][j]
        const short* Wb = (const short*)W2v;
        #pragma unroll
        for (int ks = 0; ks < 12; ++ks) {
            int cb = ks & 3;
            v8s a0 = (ks >= 8) ? Alo[0][cb] : Ahi[0][cb];
            v8s a1 = (ks >= 8) ? Alo[1][cb] : Ahi[1][cb];
            int kb = ks * 32 + quad * 8;
            #pragma unroll
            for (int nh = 0; nh < 2; ++nh) {
                int nn = nh * 64 + n0;
                v8s b0 = *(const v8s*)(Wb + (size_t)(nn + r) * 384 + kb);
                v8s b1 = *(const v8s*)(Wb + (size_t)(nn + 16 + r) * 384 + kb);
                acc[nh][0][0] = __builtin_amdgcn_mfma_f32_16x16x32_bf16(a0, b0, acc[nh][0][0], 0, 0, 0);
                acc[nh][0][1] = __builtin_amdgcn_mfma_f32_16x16x32_bf16(a0, b1, acc[nh][0][1], 0, 0, 0);
                acc[nh][1][0] = __builtin_amdgcn_mfma_f32_16x16x32_bf16(a1, b0, acc[nh][1][0], 0, 0, 0);
                acc[nh][1][1] = __builtin_amdgcn_mfma_f32_16x16x32_bf16(a1, b1, acc[nh][1][1], 0, 0, 0);
            }
        }
        #pragma unroll
        for (int nh = 0; nh < 2; ++nh)
            #pragma unroll
            for (int i = 0; i < 2; ++i)
                #pragma unroll
                for (int j = 0; j < 2; ++j)
                    #pragma unroll
                    for (int rr = 0; rr < 4; ++rr)
                        kv_s[m0 + 16 * i + quad * 4 + rr][nh * 64 + n0 + 16 * j + r] =
                            acc[nh][i][j][rr];
    }
    __syncthreads();

    if (tid < Hsz) {
        float acc = 0.f;
        #pragma unroll 8
        for (int k = 0; k < Hsz; ++k) acc = fmaf(hT[k], w1[k * Hsz + tid], acc);
        q_s[tid] = acc;
    }
    __syncthreads();

    // scores: one quad per slot j (64 per block)
    const int jl = tid >> 2, ql = tid & 3;
    const int j = jt * 64 + jl;
    float p = 0.f;
    if (j < 255) {
        #pragma unroll 8
        for (int kk = 0; kk < 32; ++kk) {
            int k = ql * 32 + ((kk + ql) & 31);   // phase-rotated, conflict-free
            p = fmaf(tanh_n(q_s[k] + kv_s[jl][k]), w2s[k], p);
        }
    }
    p = quad_rsum(p);
    if (ql == 0) s_s[jl] = (j < 255) ? p : 0.0f;
    __syncthreads();

    // partial attn_c over this block's 64 slots (two 32-slot halves)
    {
        const int dd = tid & 127, half = tid >> 7;
        float acc = 0.f;
        #pragma unroll 4
        for (int u = 0; u < 32; ++u) {
            int lj = half * 32 + u;
            int jj = jt * 64 + lj;
            if (jj < 255) acc = fmaf(s_s[lj], Hb[(size_t)jj * Hsz + dd], acc);
        }
        part[half][dd] = acc;
    }
    __syncthreads();
    if (tid < Hsz) atomicAdd(&attn_c[b * Hsz + tid], part[0][tid] + part[1][tid]);
}

// ---------------- kernel 3b: final FC ----------------
__global__ __launch_bounds__(256) void fc_out(
    const float* __restrict__ H_all, const float* __restrict__ attn_c,
    const float* __restrict__ w_fc, const float* __restrict__ b_fc,
    float* __restrict__ out) {
    const int b = blockIdx.x, tid = threadIdx.x;
    __shared__ float r_s[Hsz];
    if (tid < Hsz)
        r_s[tid] = H_all[(size_t)b * Tsz * Hsz + 255 * Hsz + tid] + attn_c[b * Hsz + tid];
    __syncthreads();
    const int o = tid >> 1, half = tid & 1;
    float acc = 0.f;
    if (o < Csz) {
        const float* wr = w_fc + (size_t)o * Hsz + half * 64;
        const float* rr = r_s + half * 64;
        #pragma unroll 8
        for (int k = 0; k < 64; ++k) acc = fmaf(rr[k], wr[k], acc);
    }
    acc += __shfl_xor(acc, 1);
    if (half == 0 && o < Csz) out[b * Csz + o] = acc + b_fc[o];
}

// ---------------- launch ----------------
extern "C" void kernel_launch(void* const* d_in, const int* in_sizes, int n_in,
                              void* d_out, int out_size, void* d_ws, size_t ws_size,
                              hipStream_t stream) {
    const float* x    = (const float*)d_in[0];
    const float* w_ih = (const float*)d_in[1];
    const float* b_ih = (const float*)d_in[2];
    const float* w_hh = (const float*)d_in[3];
    const float* b_hh = (const float*)d_in[4];
    const float* w1   = (const float*)d_in[5];
    const float* w2   = (const float*)d_in[6];
    const float* w_fc = (const float*)d_in[7];
    const float* b_fc = (const float*)d_in[8];

    float* ws = (float*)d_ws;
    float* whh_pk = ws;                               // 65536 f
    float* bias   = whh_pk + 65536;                   // 512 f
    float* attn_c = bias + 512;                       // 4096 f
    __hip_bfloat16* W2ih = (__hip_bfloat16*)(attn_c + 4096);         // 98304 f
    __hip_bfloat16* W2v  = (__hip_bfloat16*)(attn_c + 4096 + 98304); // 24576 f
    float* G      = attn_c + 4096 + 98304 + 24576;    // 8192*512 = 4194304 f
    float* H_all  = G + 4194304;                      // 1048576 f
    // total ~5.4M floats ~= 21.7 MB

    prep_kernel<<<256, 256, 0, stream>>>(w_ih, b_ih, w_hh, b_hh, w1,
                                         W2ih, W2v, whh_pk, bias, attn_c);

    dim3 gG(G4H / 64, (Bsz * Tsz) / 64);              // (8, 128)
    gemm_mfma_f32a<<<gG, 256, 0, stream>>>(x, W2ih, bias, G, Bsz * Tsz, G4H);

    lstm_seq<<<Bsz, 512, 0, stream>>>(G, whh_pk, H_all);

    kv_scores<<<Bsz * 4, 256, 0, stream>>>(H_all, W2v, w1, w2, attn_c);

    fc_out<<<Bsz, 256, 0, stream>>>(H_all, attn_c, w_fc, b_fc, (float*)d_out);
}

// Round 11
// 311.826 us; speedup vs baseline: 1.4237x; 1.0280x over previous
//
#include <hip/hip_runtime.h>
#include <hip/hip_bf16.h>

// Problem: B=32, T=256, I=128, H=128, C=100. All fp32.
// out = (h_T + attn_c_final) @ w_fc.T + b_fc; only the LAST step's attention
// matters (scan carry overwrites attn_c each step).
//
// Structure (r9 -> r10): 3 dispatches.
//  1. prep: weight conversion/packing
//  2. gemmG: G = x @ W_ih^T + bias (MFMA, split-bf16)
//  3. lstm_fused: r2's 202us recurrence + the ENTIRE attention tail fused
//     in-block (q, KV via MFMA, scores, attn partial, final FC). Rationale:
//     separate-kernel tail measured ~119us but sums to ~45us of real work;
//     the rest was 5-dispatch launch/drain overhead + cold reads. Fused, each
//     batch's H rows are L2-hot on the CU that produced them and h_T is
//     still in LDS.
// Recurrence wall (r0-r8): VALU issue + AGPR-copy tax (no VALU op sources
// AGPRs, r4 assembler proof) + latency ~= 1900 cyc/step; MFMA recurrence
// measured worse (3080 cyc/step, r8). 201us is the floor for that phase.

#define Bsz 32
#define Tsz 256
#define Isz 128
#define Hsz 128
#define Csz 100
#define G4H 512   // 4*H

typedef short v8s __attribute__((ext_vector_type(8)));   // 8 bf16 = 4 VGPRs
typedef float v4fa __attribute__((ext_vector_type(4)));  // MFMA acc

// ---------------- device helpers ----------------
__device__ __forceinline__ float2 pk_fma(float2 a, float2 b, float2 c) {
    float2 d;
    asm("v_pk_fma_f32 %0, %1, %2, %3" : "=v"(d) : "v"(a), "v"(b), "v"(c));
    return d;
}
__device__ __forceinline__ float quad_rsum(float x) {
    int t = __builtin_amdgcn_update_dpp(0, __float_as_int(x), 0xB1, 0xF, 0xF, true); // xor 1
    x += __int_as_float(t);
    t = __builtin_amdgcn_update_dpp(0, __float_as_int(x), 0x4E, 0xF, 0xF, true);     // xor 2
    x += __int_as_float(t);
    return x;
}
// 8-lane sum within aligned 8-lane groups: xor1, xor2, half-row mirror
__device__ __forceinline__ float oct_rsum(float x) {
    int t = __builtin_amdgcn_update_dpp(0, __float_as_int(x), 0xB1, 0xF, 0xF, true);
    x += __int_as_float(t);
    t = __builtin_amdgcn_update_dpp(0, __float_as_int(x), 0x4E, 0xF, 0xF, true);
    x += __int_as_float(t);
    t = __builtin_amdgcn_update_dpp(0, __float_as_int(x), 0x141, 0xF, 0xF, true);
    x += __int_as_float(t);
    return x;
}
__device__ __forceinline__ float rcpf(float x) { return __builtin_amdgcn_rcpf(x); }
__device__ __forceinline__ float ex2(float x) { return __builtin_amdgcn_exp2f(x); }
__device__ __forceinline__ float sigm_n(float x) {
    return rcpf(1.0f + ex2(-1.442695041f * x));
}
__device__ __forceinline__ float tanh_n(float x) {
    return fmaf(-2.0f, rcpf(1.0f + ex2(2.885390082f * x)), 1.0f);
}
__device__ __forceinline__ short bf16_bits(float x) {
    __hip_bfloat16 h = __float2bfloat16(x);
    return *reinterpret_cast<short*>(&h);
}
__device__ __forceinline__ float bf16_val(float x) {
    return __bfloat162float(__float2bfloat16(x));
}

// ---------------- kernel 0: weight prep ----------------
// whh_pk: packed for lstm (r2 layout). bias = b_ih + b_hh.
// W2ih[n][k'] (512 x 384 bf16): [w_hi | w_lo | w_hi]  (pairs with A=[hi|hi|lo])
// W2v [n][k'] (128 x 384 bf16): transpose-split of w1 bottom half.
__global__ __launch_bounds__(256) void prep_kernel(
    const float* __restrict__ w_ih, const float* __restrict__ b_ih,
    const float* __restrict__ w_hh, const float* __restrict__ b_hh,
    const float* __restrict__ w1,
    __hip_bfloat16* __restrict__ W2ih, __hip_bfloat16* __restrict__ W2v,
    float* __restrict__ whh_pk, float* __restrict__ bias) {
    int idx = blockIdx.x * blockDim.x + threadIdx.x;   // 0..65535
    if (idx < G4H * Isz) {
        int n = idx >> 7;
        int k = idx & 127;
        float x = w_ih[idx];
        __hip_bfloat16 hi = __float2bfloat16(x);
        __hip_bfloat16 lo = __float2bfloat16(x - __bfloat162float(hi));
        W2ih[(size_t)n * 384 + k] = hi;
        W2ih[(size_t)n * 384 + 128 + k] = lo;
        W2ih[(size_t)n * 384 + 256 + k] = hi;

        int j4  = idx & 3;
        int q   = (idx >> 2) & 3;
        int d   = (idx >> 4) & 127;
        int gi  = (idx >> 11) & 3;
        int kk4 = (idx >> 13) & 7;
        whh_pk[idx] = w_hh[(size_t)((gi << 7) + d) * 128 + (q << 5) + (kk4 << 2) + j4];
    }
    if (idx < Hsz * Hsz) {
        int n = idx >> 7;          // output col of KV
        int k = idx & 127;
        float x = w1[(size_t)(128 + k) * Hsz + n];
        __hip_bfloat16 hi = __float2bfloat16(x);
        __hip_bfloat16 lo = __float2bfloat16(x - __bfloat162float(hi));
        W2v[(size_t)n * 384 + k] = hi;
        W2v[(size_t)n * 384 + 128 + k] = lo;
        W2v[(size_t)n * 384 + 256 + k] = hi;
    }
    if (idx < G4H) bias[idx] = b_ih[idx] + b_hh[idx];
}

// ---------------- gemm_mfma_f32a: C[M,N] = split(A_fp32) @ split(W)^T (+bias) ----
__global__ __launch_bounds__(256) void gemm_mfma_f32a(
    const float* __restrict__ A, const __hip_bfloat16* __restrict__ W2,
    const float* __restrict__ bias, float* __restrict__ C, int M, int N) {
    const int tid = threadIdx.x;
    const int w = tid >> 6, lane = tid & 63;
    const int m0 = blockIdx.y * 64 + (w & 1) * 32;
    const int n0 = blockIdx.x * 64 + (w >> 1) * 32;
    const int r = lane & 15, quad = lane >> 4;

    v8s Ahi[2][4], Alo[2][4];
    #pragma unroll
    for (int i = 0; i < 2; ++i)
        #pragma unroll
        for (int cb = 0; cb < 4; ++cb) {
            const float* src = A + (size_t)(m0 + 16 * i + r) * Isz + cb * 32 + quad * 8;
            float4 f0 = *(const float4*)src;
            float4 f1 = *(const float4*)(src + 4);
            float f[8] = {f0.x, f0.y, f0.z, f0.w, f1.x, f1.y, f1.z, f1.w};
            v8s hi, lo;
            #pragma unroll
            for (int e = 0; e < 8; ++e) {
                float hv = bf16_val(f[e]);
                hi[e] = bf16_bits(f[e]);
                lo[e] = bf16_bits(f[e] - hv);
            }
            Ahi[i][cb] = hi;
            Alo[i][cb] = lo;
        }

    v4fa acc[2][2] = {};
    const short* Wb = (const short*)W2;
    #pragma unroll
    for (int ks = 0; ks < 12; ++ks) {
        int cb = ks & 3;
        v8s a0 = (ks >= 8) ? Alo[0][cb] : Ahi[0][cb];
        v8s a1 = (ks >= 8) ? Alo[1][cb] : Ahi[1][cb];
        int kb = ks * 32 + quad * 8;
        v8s b0 = *(const v8s*)(Wb + (size_t)(n0 + r) * 384 + kb);
        v8s b1 = *(const v8s*)(Wb + (size_t)(n0 + 16 + r) * 384 + kb);
        acc[0][0] = __builtin_amdgcn_mfma_f32_16x16x32_bf16(a0, b0, acc[0][0], 0, 0, 0);
        acc[0][1] = __builtin_amdgcn_mfma_f32_16x16x32_bf16(a0, b1, acc[0][1], 0, 0, 0);
        acc[1][0] = __builtin_amdgcn_mfma_f32_16x16x32_bf16(a1, b0, acc[1][0], 0, 0, 0);
        acc[1][1] = __builtin_amdgcn_mfma_f32_16x16x32_bf16(a1, b1, acc[1][1], 0, 0, 0);
    }
    // C/D layout: col = lane&15, row = quad*4 + reg  [verified m89/m91]
    #pragma unroll
    for (int i = 0; i < 2; ++i)
        #pragma unroll
        for (int j = 0; j < 2; ++j) {
            int cn = n0 + 16 * j + r;
            float bb = bias ? bias[cn] : 0.0f;
            #pragma unroll
            for (int rr = 0; rr < 4; ++rr) {
                int row = m0 + 16 * i + quad * 4 + rr;
                C[(size_t)row * N + cn] = acc[i][j][rr] + bb;
            }
        }
}

// ---------------- kernel 2: sequential LSTM + fused attention tail ----------------
#define HPAD(k) ((k) + 8 * ((k) >> 5))

__global__ __launch_bounds__(512, 2) void lstm_fused(
    const float* __restrict__ G, const float* __restrict__ whh_pk,
    const __hip_bfloat16* __restrict__ W2v,
    const float* __restrict__ w1, const float* __restrict__ w2,
    const float* __restrict__ w_fc, const float* __restrict__ b_fc,
    float* __restrict__ H_all, float* __restrict__ out) {
    const int b = blockIdx.x;
    const int tid = threadIdx.x;
    const int d = tid >> 2;
    const int q = tid & 3;

    __shared__ float h_s[2][160];
    __shared__ float kv_s[64][132];
    __shared__ float hT_s[Hsz];
    __shared__ float q_s[Hsz];
    __shared__ float w2s[Hsz];
    __shared__ float r_s[Hsz];
    __shared__ float s_s[64];
    __shared__ float part4[4][Hsz];

    // ================= recurrence (r2 structure, 201us) =================
    float2 w2v[4][16];
    {
        const float4* wp = (const float4*)whh_pk;
        #pragma unroll
        for (int kk4 = 0; kk4 < 8; ++kk4)
            #pragma unroll
            for (int gi = 0; gi < 4; ++gi) {
                float4 v = wp[((kk4 * 4 + gi) * 128 + d) * 4 + q];
                w2v[gi][kk4 * 2]     = make_float2(v.x, v.y);
                w2v[gi][kk4 * 2 + 1] = make_float2(v.z, v.w);
            }
    }

    if (tid < 320) ((float*)h_s)[tid] = 0.0f;
    float c = 0.0f;
    __syncthreads();   // once, before the loop: full drain is fine here

    const float* Gq = G + (size_t)b * Tsz * G4H + q * 128 + d;
    float* Hst = H_all + (size_t)b * Tsz * Hsz + d;

    float gval = Gq[0];
    int cur = 0;
    for (int t = 0; t < Tsz; ++t) {
        const int tn = (t < Tsz - 1) ? t + 1 : t;
        float ngval = Gq[(size_t)tn * G4H];   // prefetch; stays in flight
                                              // across the raw barrier

        float2 accA[4], accB[4];
        #pragma unroll
        for (int gi = 0; gi < 4; ++gi) {
            accA[gi] = make_float2(q == gi ? gval : 0.f, 0.f);
            accB[gi] = make_float2(0.f, 0.f);
        }
        const float4* hb4 = (const float4*)&h_s[cur][q * 40];  // HPAD(q*32)=q*40
        #pragma unroll
        for (int kk4 = 0; kk4 < 8; ++kk4) {
            float4 h4 = hb4[kk4];
            float2 hA = make_float2(h4.x, h4.y);
            float2 hB = make_float2(h4.z, h4.w);
            accA[0] = pk_fma(hA, w2v[0][2 * kk4], accA[0]);
            accA[1] = pk_fma(hA, w2v[1][2 * kk4], accA[1]);
            accA[2] = pk_fma(hA, w2v[2][2 * kk4], accA[2]);
            accA[3] = pk_fma(hA, w2v[3][2 * kk4], accA[3]);
            accB[0] = pk_fma(hB, w2v[0][2 * kk4 + 1], accB[0]);
            accB[1] = pk_fma(hB, w2v[1][2 * kk4 + 1], accB[1]);
            accB[2] = pk_fma(hB, w2v[2][2 * kk4 + 1], accB[2]);
            accB[3] = pk_fma(hB, w2v[3][2 * kk4 + 1], accB[3]);
        }
        float a0 = quad_rsum(accA[0].x + accA[0].y + accB[0].x + accB[0].y);
        float a1 = quad_rsum(accA[1].x + accA[1].y + accB[1].x + accB[1].y);
        float a2 = quad_rsum(accA[2].x + accA[2].y + accB[2].x + accB[2].y);
        float a3 = quad_rsum(accA[3].x + accA[3].y + accB[3].x + accB[3].y);

        float iv = sigm_n(a0);
        float fv = sigm_n(a1);
        float gv = tanh_n(a2);
        float ov = sigm_n(a3);
        c = fmaf(fv, c, iv * gv);
        float h = ov * tanh_n(c);

        if (q == 0) {
            h_s[cur ^ 1][HPAD(d)] = h;
            Hst[(size_t)t * Hsz] = h;
        }
        gval = ngval;
        // ---- raw barrier: wait LDS only, leave global load/store in flight
        __builtin_amdgcn_sched_barrier(0);
        asm volatile("s_waitcnt lgkmcnt(0)" ::: "memory");
        __builtin_amdgcn_s_barrier();
        __builtin_amdgcn_sched_barrier(0);
        cur ^= 1;
    }

    // ================= fused attention tail =================
    // h_s[cur] holds h(255). Full drain so every wave's H_all stores are
    // complete/visible (same-block global RAW after __syncthreads is defined).
    __syncthreads();

    const float* Hb = H_all + (size_t)b * Tsz * Hsz;
    const int n_a = tid >> 2;          // 0..127 (reuses q as lane-in-quad)

    // Phase A: q_s = hT @ w1_top; stage hT and w2 in LDS
    {
        if (tid < Hsz) {
            hT_s[tid] = h_s[cur][HPAD(tid)];
            w2s[tid] = w2[tid];
        }
        float acc = 0.f;
        #pragma unroll 8
        for (int kk = 0; kk < 32; ++kk) {
            int k = q * 32 + kk;
            acc = fmaf(h_s[cur][HPAD(k)], w1[(size_t)k * Hsz + n_a], acc);
        }
        acc = quad_rsum(acc);
        if (q == 0) q_s[n_a] = acc;
    }
    __syncthreads();

    // Phase B: 4 jt-tiles of 64 slots: KV (MFMA) -> scores -> attn partial
    const int w_id = tid >> 6;
    const int lane = tid & 63;
    const int fr = lane & 15, fq = lane >> 4;
    const int d_att = tid & 127, grp = tid >> 7;
    float racc = 0.f;                 // this thread's attn_c partial

    for (int jt = 0; jt < 4; ++jt) {
        // B1: KV tile rows jt*64..+64, cols 0..128, 8 waves (one 32x32 each)
        {
            const int m0 = (w_id & 1) * 32;
            const int n0 = (w_id >> 1) * 32;
            const float* Abase = Hb + (size_t)(jt * 64) * Hsz;

            v8s Ahi[2][4], Alo[2][4];
            #pragma unroll
            for (int i = 0; i < 2; ++i)
                #pragma unroll
                for (int cb = 0; cb < 4; ++cb) {
                    const float* src = Abase + (size_t)(m0 + 16 * i + fr) * Hsz + cb * 32 + fq * 8;
                    float4 f0 = *(const float4*)src;
                    float4 f1 = *(const float4*)(src + 4);
                    float f[8] = {f0.x, f0.y, f0.z, f0.w, f1.x, f1.y, f1.z, f1.w};
                    v8s hi, lo;
                    #pragma unroll
                    for (int e = 0; e < 8; ++e) {
                        float hv = bf16_val(f[e]);
                        hi[e] = bf16_bits(f[e]);
                        lo[e] = bf16_bits(f[e] - hv);
                    }
                    Ahi[i][cb] = hi;
                    Alo[i][cb] = lo;
                }

            v4fa a2[2][2] = {};
            const short* Wb = (const short*)W2v;
            #pragma unroll
            for (int ks = 0; ks < 12; ++ks) {
                int cb = ks & 3;
                v8s a0 = (ks >= 8) ? Alo[0][cb] : Ahi[0][cb];
                v8s a1 = (ks >= 8) ? Alo[1][cb] : Ahi[1][cb];
                int kb = ks * 32 + fq * 8;
                v8s b0 = *(const v8s*)(Wb + (size_t)(n0 + fr) * 384 + kb);
                v8s b1 = *(const v8s*)(Wb + (size_t)(n0 + 16 + fr) * 384 + kb);
                a2[0][0] = __builtin_amdgcn_mfma_f32_16x16x32_bf16(a0, b0, a2[0][0], 0, 0, 0);
                a2[0][1] = __builtin_amdgcn_mfma_f32_16x16x32_bf16(a0, b1, a2[0][1], 0, 0, 0);
                a2[1][0] = __builtin_amdgcn_mfma_f32_16x16x32_bf16(a1, b0, a2[1][0], 0, 0, 0);
                a2[1][1] = __builtin_amdgcn_mfma_f32_16x16x32_bf16(a1, b1, a2[1][1], 0, 0, 0);
            }
            #pragma unroll
            for (int i = 0; i < 2; ++i)
                #pragma unroll
                for (int j = 0; j < 2; ++j)
                    #pragma unroll
                    for (int rr = 0; rr < 4; ++rr)
                        kv_s[m0 + 16 * i + fq * 4 + rr][n0 + 16 * j + fr] = a2[i][j][rr];
        }
        __syncthreads();

        // B2: scores, one 8-lane group per slot (64 slots)
        {
            const int jl = tid >> 3, oct = tid & 7;
            float p = 0.f;
            #pragma unroll
            for (int kk = 0; kk < 16; ++kk) {
                int k = oct * 16 + kk;
                p = fmaf(tanh_n(q_s[k] + kv_s[jl][k]), w2s[k], p);
            }
            p = oct_rsum(p);
            if (oct == 0) s_s[jl] = (jt * 64 + jl < 255) ? p : 0.0f;
        }
        __syncthreads();

        // B3: attn partial: racc += s[j] * H[j][d] over this tile's 16 j/grp
        #pragma unroll 4
        for (int u = 0; u < 16; ++u) {
            int lj = grp * 16 + u;
            racc = fmaf(s_s[lj], Hb[(size_t)(jt * 64 + lj) * Hsz + d_att], racc);
        }
        __syncthreads();   // protect kv_s / s_s before next jt overwrites
    }

    part4[grp][d_att] = racc;
    __syncthreads();
    if (tid < Hsz)
        r_s[tid] = hT_s[tid] + part4[0][tid] + part4[1][tid] + part4[2][tid] + part4[3][tid];
    __syncthreads();

    // Phase C: out[b] = r @ w_fc^T + b_fc (one quad per output)
    {
        const int o = tid >> 2;
        float acc = 0.f;
        if (o < Csz) {
            #pragma unroll 8
            for (int kk = 0; kk < 32; ++kk) {
                int k = q * 32 + kk;
                acc = fmaf(r_s[k], w_fc[(size_t)o * Hsz + k], acc);
            }
        }
        acc = quad_rsum(acc);
        if (q == 0 && o < Csz) out[b * Csz + o] = acc + b_fc[o];
    }
}

// ---------------- launch ----------------
extern "C" void kernel_launch(void* const* d_in, const int* in_sizes, int n_in,
                              void* d_out, int out_size, void* d_ws, size_t ws_size,
                              hipStream_t stream) {
    const float* x    = (const float*)d_in[0];
    const float* w_ih = (const float*)d_in[1];
    const float* b_ih = (const float*)d_in[2];
    const float* w_hh = (const float*)d_in[3];
    const float* b_hh = (const float*)d_in[4];
    const float* w1   = (const float*)d_in[5];
    const float* w2   = (const float*)d_in[6];
    const float* w_fc = (const float*)d_in[7];
    const float* b_fc = (const float*)d_in[8];

    float* ws = (float*)d_ws;
    float* whh_pk = ws;                               // 65536 f
    float* bias   = whh_pk + 65536;                   // 512 f
    __hip_bfloat16* W2ih = (__hip_bfloat16*)(bias + 512);            // 98304 f
    __hip_bfloat16* W2v  = (__hip_bfloat16*)(bias + 512 + 98304);    // 24576 f
    float* G      = bias + 512 + 98304 + 24576;       // 8192*512 = 4194304 f
    float* H_all  = G + 4194304;                      // 1048576 f
    // total ~5.43M floats ~= 21.7 MB

    prep_kernel<<<256, 256, 0, stream>>>(w_ih, b_ih, w_hh, b_hh, w1,
                                         W2ih, W2v, whh_pk, bias);

    dim3 gG(G4H / 64, (Bsz * Tsz) / 64);              // (8, 128)
    gemm_mfma_f32a<<<gG, 256, 0, stream>>>(x, W2ih, bias, G, Bsz * Tsz, G4H);

    lstm_fused<<<Bsz, 512, 0, stream>>>(G, whh_pk, W2v, w1, w2, w_fc, b_fc,
                                        H_all, (float*)d_out);
}